// Round 6
// baseline (10362.023 us; speedup 1.0000x reference)
//
#include <hip/hip_runtime.h>
#include <hip/hip_bf16.h>

#define SEQ   512
#define BATCH 128
#define XD    256
#define PHID  512
#define RD    256
#define OUTD  256
#define NBLK  32

typedef __attribute__((ext_vector_type(8))) short short8;
typedef __attribute__((ext_vector_type(4))) float floatx4;
typedef unsigned long long u64;

#define MFMA(a, b, c) __builtin_amdgcn_mfma_f32_16x16x32_bf16((a), (b), (c), 0, 0, 0)

__device__ inline short8 ldg8(const __hip_bfloat16* p) {       // cached (x, LDS)
    return *reinterpret_cast<const short8*>(p);
}
// Device-coherent 16B load = two relaxed agent-scope 8B atomic loads (sc1:
// bypasses non-coherent caches, reads the LLC coherent point, no waitcnts).
__device__ inline short8 lda16(const __hip_bfloat16* p) {
    union { u64 u[2]; short8 s; } c;
    c.u[0] = __hip_atomic_load((const u64*)p,     __ATOMIC_RELAXED, __HIP_MEMORY_SCOPE_AGENT);
    c.u[1] = __hip_atomic_load((const u64*)p + 1, __ATOMIC_RELAXED, __HIP_MEMORY_SCOPE_AGENT);
    return c.s;
}
// Sign-parity-tagged 2B store of a ReLU value (v >= 0 -> sign bit 0), then
// XOR the sign with the step parity. Consumers validate sign==parity per
// element, so NO drain/flag/fence is needed anywhere.
__device__ inline void st_tag(__hip_bfloat16* p, float v, unsigned sgn) {
    union { __hip_bfloat16 b; unsigned short u; } c;
    c.b = __float2bfloat16(v);
    unsigned short raw = (unsigned short)((c.u & 0x7fffu) ^ (sgn << 15));
    __hip_atomic_store((unsigned short*)p, raw, __ATOMIC_RELAXED, __HIP_MEMORY_SCOPE_AGENT);
}
// Validity: all 8 bf16 sign bits must equal parity p.
__device__ inline bool validp(short8 v, unsigned p) {
    union { short8 s; unsigned u[4]; } c; c.s = v;
    if (p) return (((c.u[0] & c.u[1] & c.u[2] & c.u[3]) & 0x80008000u) == 0x80008000u);
    return (((c.u[0] | c.u[1] | c.u[2] | c.u[3]) & 0x80008000u) == 0u);
}
__device__ inline short8 strip(short8 v) {
    union { short8 s; unsigned u[4]; } c; c.s = v;
    c.u[0] &= 0x7fff7fffu; c.u[1] &= 0x7fff7fffu;
    c.u[2] &= 0x7fff7fffu; c.u[3] &= 0x7fff7fffu;
    return c.s;
}

__global__ void convert_x(const float* __restrict__ x, __hip_bfloat16* __restrict__ xbf) {
    const int gid = blockIdx.x * blockDim.x + threadIdx.x;
    const float4 v = reinterpret_cast<const float4*>(x)[gid];
    __hip_bfloat16* d = xbf + 4 * (size_t)gid;
    d[0] = __float2bfloat16(v.x); d[1] = __float2bfloat16(v.y);
    d[2] = __float2bfloat16(v.z); d[3] = __float2bfloat16(v.w);
}

// 32 persistent blocks x 512 threads (8 waves); wave w owns batch rows
// [16w, 16w+16) -- 8 independent row-group pipelines, zero flags, zero
// fences: all cross-block handoff is sign-parity-tagged data polled at the
// LLC coherent point.  phi ring depth 4 (parity (t>>2)&1), r single-buffered
// (parity t&1); ring-overwrite safety follows from the r->phi->s dependency
// chain (a slot is rewritten only 4 steps after its consumers advanced).
//   bid  0..15 : phi-blocks — 32 phi-cols; x-part GEMM overlaps the r-poll
//   bid 16..31 : s-blocks   — 16 r-cols + 16 out-cols; s_a = mu_a@W1_a^T and
//                o_a = mu_a@Wo_a^T in registers; o-GEMM off the critical path
__global__ void __launch_bounds__(512, 2) sru_pipe(
    const float* __restrict__ W1, const float* __restrict__ W2,
    const float* __restrict__ Wo,
    const float* __restrict__ b1, const float* __restrict__ b2,
    const float* __restrict__ bo,
    const __hip_bfloat16* __restrict__ xbf,
    __hip_bfloat16* __restrict__ rbf,
    __hip_bfloat16* __restrict__ phib,
    float* __restrict__ out)
{
    __shared__ __hip_bfloat16 wlds[65536];   // 128 KB (s-blocks: W1 + Wo)
    const int bid  = blockIdx.x;
    const int tid  = threadIdx.x;
    const int wave = tid >> 6;
    const int lane = tid & 63;
    const int quad = lane >> 4;
    const int lrow = lane & 15;
    const int m0   = wave * 16;              // 16 rows per wave
    const float pre[4]  = {0.f, 1.f, 9.f, 99.f};    // alpha/(1-alpha)
    const float post[4] = {1.f, 0.5f, 0.1f, 0.01f}; // (1-alpha)

    if (bid < 16) {
        // ================= phi-block =================
        const int j0 = bid * 32;
        for (int i = tid * 4; i < 2 * 32 * 256; i += 2048) {
            const int part = i >> 13, rem = i & 8191;
            const int n = rem >> 8, k = rem & 255;
            const float4 v = *reinterpret_cast<const float4*>(
                &W2[(j0 + n) * (XD + RD) + part * 256 + k]);
            __hip_bfloat16* dst = &wlds[(((part * 32 + (k >> 3)) * 32 + n) << 3) + (k & 7)];
            dst[0] = __float2bfloat16(v.x); dst[1] = __float2bfloat16(v.y);
            dst[2] = __float2bfloat16(v.z); dst[3] = __float2bfloat16(v.w);
        }
        __syncthreads();
        const float bj0 = b2[j0 + lrow];
        const float bj1 = b2[j0 + 16 + lrow];
        #pragma unroll 1
        for (int t = 0; t < SEQ; ++t) {
            floatx4 acc[2] = {};
            // x-part (cached loads; independent of r_t) — overlaps the r wait
            const __hip_bfloat16* xt = xbf + ((size_t)t * BATCH + m0 + lrow) * XD + 8 * quad;
            #pragma unroll
            for (int ki = 0; ki < 8; ++ki) {
                const short8 a0 = ldg8(xt + 32 * ki);
                #pragma unroll
                for (int j2 = 0; j2 < 2; ++j2) {
                    const short8 b = ldg8(&wlds[(((4 * ki + quad) * 32 + j2 * 16 + lrow) << 3)]);
                    acc[j2] = MFMA(a0, b, acc[j2]);
                }
            }
            // r_t: speculative batched coherent loads + sign-parity validate
            const unsigned rpar = (unsigned)(t & 1);
            const __hip_bfloat16* r0 = rbf + (m0 + lrow) * RD + 8 * quad;
            short8 ra[8];
            #pragma unroll
            for (int j = 0; j < 8; ++j) ra[j] = lda16(r0 + 32 * j);
            for (;;) {
                unsigned bad = 0;
                #pragma unroll
                for (int j = 0; j < 8; ++j) if (!validp(ra[j], rpar)) bad |= 1u << j;
                if (!bad) break;
                #pragma unroll
                for (int j = 0; j < 8; ++j) if (bad & (1u << j)) ra[j] = lda16(r0 + 32 * j);
            }
            #pragma unroll
            for (int j = 0; j < 8; ++j) ra[j] = strip(ra[j]);
            // r-part GEMM
            #pragma unroll
            for (int j = 0; j < 8; ++j) {
                #pragma unroll
                for (int j2 = 0; j2 < 2; ++j2) {
                    const short8 b = ldg8(&wlds[(((32 + 4 * j + quad) * 32 + j2 * 16 + lrow) << 3)]);
                    acc[j2] = MFMA(ra[j], b, acc[j2]);
                }
            }
            // publish phi_t into ring slot t&3, sign-tagged with (t>>2)&1
            const unsigned psgn = (unsigned)((t >> 2) & 1);
            __hip_bfloat16* pb = phib + (size_t)(t & 3) * BATCH * PHID;
            #pragma unroll
            for (int j2 = 0; j2 < 2; ++j2)
                #pragma unroll
                for (int i = 0; i < 4; ++i) {
                    const int row = m0 + quad * 4 + i;
                    st_tag(&pb[row * PHID + j0 + j2 * 16 + lrow],
                           fmaxf(acc[j2][i] + (j2 ? bj1 : bj0), 0.f), psgn);
                }
            // no drain, no flag — consumers self-validate
        }
    } else {
        // ================= s-block (s + o fused) =================
        const int sb = bid - 16, j0 = sb * 16;
        for (int i = tid * 4; i < 65536; i += 2048) {
            const int mtx = i >> 15;                 // 0 = W1, 1 = Wo
            const int r3 = i & 32767;
            const int a = r3 >> 13, rem = r3 & 8191;
            const int n = rem >> 9, k = rem & 511;
            const float* src = mtx ? Wo : W1;
            const float4 v = *reinterpret_cast<const float4*>(
                &src[(j0 + n) * 2048 + a * 512 + k]);
            __hip_bfloat16* dst = &wlds[mtx * 32768 + (((a * 64 + (k >> 3)) * 16 + n) << 3) + (k & 7)];
            dst[0] = __float2bfloat16(v.x); dst[1] = __float2bfloat16(v.y);
            dst[2] = __float2bfloat16(v.z); dst[3] = __float2bfloat16(v.w);
        }
        __syncthreads();
        const float bjv = b1[j0 + lrow];
        floatx4 s[4] = {};
        floatx4 o[4] = {};
        // publish r_0 = relu(b1), parity 0
        #pragma unroll
        for (int i = 0; i < 4; ++i)
            st_tag(&rbf[(m0 + quad * 4 + i) * RD + j0 + lrow], fmaxf(bjv, 0.f), 0u);
        #pragma unroll 1
        for (int t = 0; t < SEQ; ++t) {
            // phi_t: speculative batched coherent loads + validate
            const unsigned ppar = (unsigned)((t >> 2) & 1);
            const __hip_bfloat16* p0 = phib + (size_t)(t & 3) * BATCH * PHID
                                     + (m0 + lrow) * PHID + 8 * quad;
            short8 pa[16];
            #pragma unroll
            for (int j = 0; j < 16; ++j) pa[j] = lda16(p0 + 32 * j);
            for (;;) {
                unsigned bad = 0;
                #pragma unroll
                for (int j = 0; j < 16; ++j) if (!validp(pa[j], ppar)) bad |= 1u << j;
                if (!bad) break;
                #pragma unroll
                for (int j = 0; j < 16; ++j) if (bad & (1u << j)) pa[j] = lda16(p0 + 32 * j);
            }
            #pragma unroll
            for (int j = 0; j < 16; ++j) pa[j] = strip(pa[j]);
            // s-update (critical path)
            #pragma unroll
            for (int a = 0; a < 4; ++a) s[a] *= pre[a];
            #pragma unroll
            for (int j = 0; j < 16; ++j) {
                #pragma unroll
                for (int a = 0; a < 4; ++a) {
                    const short8 b = ldg8(&wlds[(((a * 64 + 4 * j + quad) * 16 + lrow) << 3)]);
                    s[a] = MFMA(pa[j], b, s[a]);
                }
            }
            #pragma unroll
            for (int a = 0; a < 4; ++a) s[a] *= post[a];
            // publish r_{t+1} ASAP, parity (t+1)&1
            if (t < SEQ - 1) {
                const unsigned rsgn = (unsigned)((t + 1) & 1);
                #pragma unroll
                for (int i = 0; i < 4; ++i) {
                    const float rv = s[0][i] + s[1][i] + s[2][i] + s[3][i] + bjv;
                    st_tag(&rbf[(m0 + quad * 4 + i) * RD + j0 + lrow], fmaxf(rv, 0.f), rsgn);
                }
            }
            // o-update off the critical path, reusing validated phi registers
            #pragma unroll
            for (int a = 0; a < 4; ++a) o[a] *= pre[a];
            #pragma unroll
            for (int j = 0; j < 16; ++j) {
                #pragma unroll
                for (int a = 0; a < 4; ++a) {
                    const short8 b = ldg8(&wlds[32768 + (((a * 64 + 4 * j + quad) * 16 + lrow) << 3)]);
                    o[a] = MFMA(pa[j], b, o[a]);
                }
            }
            #pragma unroll
            for (int a = 0; a < 4; ++a) o[a] *= post[a];
        }
        const float bjo = bo[j0 + lrow];
        #pragma unroll
        for (int i = 0; i < 4; ++i) {
            const int row = m0 + quad * 4 + i;
            const float v = o[0][i] + o[1][i] + o[2][i] + o[3][i] + bjo;
            out[row * OUTD + j0 + lrow] = fmaxf(v, 0.f);
        }
    }
}

extern "C" void kernel_launch(void* const* d_in, const int* in_sizes, int n_in,
                              void* d_out, int out_size, void* d_ws, size_t ws_size,
                              hipStream_t stream)
{
    const float* x  = (const float*)d_in[0];
    const float* W1 = (const float*)d_in[1];
    const float* b1 = (const float*)d_in[2];
    const float* W2 = (const float*)d_in[3];
    const float* b2 = (const float*)d_in[4];
    const float* Wo = (const float*)d_in[5];
    const float* bo = (const float*)d_in[6];
    float* out = (float*)d_out;
    char* ws = (char*)d_ws;

    constexpr size_t O_RBF  = 0;                                 // 128x256 bf16 = 64 KB
    constexpr size_t O_PHI  = O_RBF + (size_t)BATCH * RD * 2;    // 4 x 128x512 bf16 = 512 KB
    constexpr size_t O_X    = O_PHI + 4ull * BATCH * PHID * 2;   // 32 MB

    // Guarantee the sign=1 poison pattern in rbf/phib regardless of harness
    // state (0xAAAA bf16 has sign bit 1 == "invalid for first use").
    hipMemsetAsync(ws + O_RBF, 0xAA, O_X, stream);
    convert_x<<<SEQ * BATCH * XD / 4 / 256, 256, 0, stream>>>(
        x, (__hip_bfloat16*)(ws + O_X));
    sru_pipe<<<NBLK, 512, 0, stream>>>(
        W1, W2, Wo, b1, b2, bo,
        (const __hip_bfloat16*)(ws + O_X),
        (__hip_bfloat16*)(ws + O_RBF),
        (__hip_bfloat16*)(ws + O_PHI),
        out);
}